// Round 1
// 617.020 us; speedup vs baseline: 1.0120x; 1.0120x over previous
//
#include <hip/hip_runtime.h>
#include <math.h>

// Problem constants
#define S_LEN 2048
#define HID 4096
#define NH 32
#define NKV 8
#define HD 128
#define QKV_N ((NH + 2*NKV) * HD)   // 6144
#define NQK (NH + NKV)              // 40
static __device__ __constant__ const float SCALE_F = 0.08838834764831845f; // 128^-0.5

typedef __bf16 bf16x8 __attribute__((ext_vector_type(8)));
typedef __bf16 bf16x4 __attribute__((ext_vector_type(4)));
typedef float  f32x4  __attribute__((ext_vector_type(4)));

#define GLD_LDS(gptr, lptr) \
  __builtin_amdgcn_global_load_lds( \
      (const __attribute__((address_space(1))) uint32_t*)(gptr), \
      (__attribute__((address_space(3))) uint32_t*)(lptr), 16, 0, 0)

// ---------- cast fp32 -> bf16 (vectorized) ----------
__global__ void cast_bf16_kernel(const float4* __restrict__ in, __bf16* __restrict__ out, int n4) {
  int i = blockIdx.x * blockDim.x + threadIdx.x;
  if (i >= n4) return;
  float4 v = in[i];
  bf16x4 o = { (__bf16)v.x, (__bf16)v.y, (__bf16)v.z, (__bf16)v.w };
  *(bf16x4*)(out + (size_t)i * 4) = o;
}

// ---------- transpose + cast: in[R][C] fp32 -> out[C][R] bf16 ----------
__global__ void transpose_cast_kernel(const float* __restrict__ in, __bf16* __restrict__ out,
                                      int R, int C) {
  __shared__ float tile[32][33];
  int bx = blockIdx.x * 32;  // col of in
  int by = blockIdx.y * 32;  // row of in
  int tx = threadIdx.x, ty = threadIdx.y;
  for (int i = 0; i < 32; i += 8)
    tile[ty + i][tx] = in[(size_t)(by + ty + i) * C + bx + tx];
  __syncthreads();
  for (int i = 0; i < 32; i += 8)
    out[(size_t)(bx + ty + i) * R + by + tx] = (__bf16)tile[tx][ty + i];
}

// ---------- V transpose: Vt[kvh][d][s] = qkv[s][(NH+NKV)*HD + kvh*HD + d] ----------
__global__ void transpose_v_kernel(const __bf16* __restrict__ qkv, __bf16* __restrict__ Vt) {
  __shared__ __bf16 tile[32][33];
  int kvh = blockIdx.z;
  int sb = blockIdx.x * 32;
  int db = blockIdx.y * 32;
  int tx = threadIdx.x, ty = threadIdx.y;
  const __bf16* src = qkv + (size_t)(NH + NKV) * HD + (size_t)kvh * HD;
  for (int i = 0; i < 32; i += 8)
    tile[ty + i][tx] = src[(size_t)(sb + ty + i) * QKV_N + db + tx];
  __syncthreads();
  for (int i = 0; i < 32; i += 8)
    Vt[((size_t)kvh * HD + db + ty + i) * S_LEN + sb + tx] = tile[tx][ty + i];
}

// ---------- RoPE: split qkv -> Qr [S][NH][HD], Kr [S][NKV][HD] with rotation ----------
__global__ void rope_kernel(const __bf16* __restrict__ qkv, const int* __restrict__ pos,
                            __bf16* __restrict__ Qr, __bf16* __restrict__ Kr) {
  int idx = blockIdx.x * blockDim.x + threadIdx.x;
  int half = idx & 63;         // 0..63
  int t = idx >> 6;
  int hh = t % NQK;
  int s = t / NQK;
  if (s >= S_LEN) return;
  float p = (float)pos[s];
  float inv_freq = exp2f((float)half * -0.2076205059304601f);
  float ang = p * inv_freq;
  float cs = cosf(ang), sn = sinf(ang);
  const __bf16* src; __bf16* dst;
  if (hh < NH) {
    src = qkv + (size_t)s * QKV_N + (size_t)hh * HD;
    dst = Qr + ((size_t)s * NH + hh) * HD;
  } else {
    int kh = hh - NH;
    src = qkv + (size_t)s * QKV_N + (size_t)NH * HD + (size_t)kh * HD;
    dst = Kr + ((size_t)s * NKV + kh) * HD;
  }
  float x1 = (float)src[half], x2 = (float)src[half + 64];
  dst[half]      = (__bf16)(x1 * cs - x2 * sn);
  dst[half + 64] = (__bf16)(x2 * cs + x1 * sn);
}

// ===================================================================================
// 256x256-tile 8-phase bf16 GEMM (T1-free port of the m201 schedule, plain HIP).
//   C[M][N] = A[M][K] @ Bt[N][K]^T
// Geometry: BM=BN=256, BK=64 (two 32-wide k-halves), 512 thr = 8 waves (2M x 4N),
//   per-wave output 128x64 = acc[8][4] f32x4. LDS = 2buf x 2khalf x 256x32 x (A,B)
//   = 128 KiB -> 1 block/CU, 2 waves/SIMD.
// Per phase: {4-or-8 ds_read_b128 | 1 half-tile stage (2x global_load_lds) |
//   s_barrier | setprio(1) 16xMFMA setprio(0) | [vmcnt(4) @ phases 4,8] | s_barrier}.
// Stage plan per iteration u (tiles t=2u in buf0 phases 0-3, t+1 in buf1 phases 4-7):
//   p0: Ak1(t+1)  p1: Bk1(t+1)  p2: Ak0(t+2)  p3: Bk0(t+2)+vmcnt(4)
//   p4: Ak1(t+2)  p5: Bk1(t+2)  p6: Ak0(t+3)  p7: Bk0(t+3)+vmcnt(4)
//   vmcnt(4) at p3 drains exactly {Ak0,Bk0,Ak1,Bk1}(t+1); at p7 drains tile t+2.
//   Every stage targets a region whose last ds_read finished >=1 barrier earlier.
// Bank conflicts: chunk swizzle ch ^= (row>>1)&3 on [256][32] halves (row = 64 B
//   = 16 banks; swizzle spreads 8 consecutive rows over all 32 banks -> 2-way=free).
//   Applied as inverse-swizzled GLOBAL source (gload_lds writes linearly) + swizzled
//   ds_read address (G21: both-sides-or-neither).
// ===================================================================================
template <typename OutT>
__global__ __launch_bounds__(512, 2) void gemm8p_kernel(const __bf16* __restrict__ A,
                                                        const __bf16* __restrict__ Bt,
                                                        OutT* __restrict__ C,
                                                        int M, int N, int K) {
  __shared__ __align__(16) __bf16 sA[2][2][256 * 32];
  __shared__ __align__(16) __bf16 sB[2][2][256 * 32];
  const int tid = threadIdx.x;
  const int lane = tid & 63;
  const int wave = tid >> 6;
  const int quad = lane >> 4;
  const int l16 = lane & 15;
  const int wm = (wave >> 2) * 128;   // 2 M-warps
  const int wn = (wave & 3) * 64;     // 4 N-warps
  const size_t bm = (size_t)blockIdx.y * 256;
  const size_t bn = (size_t)blockIdx.x * 256;
  const int NT = K >> 6;              // K-tiles of 64 (even: K=4096 -> 64)
  const int rsw = (l16 >> 1) & 3;     // read-side chunk swizzle

  f32x4 acc[8][4] = {};
  bf16x8 aR[4], bR[4];

#define STAGE(gbase, rowbase, tau, h, dst) do {                                   \
    size_t kof_ = (size_t)((tau) % NT) * 64 + (h) * 32;                           \
    _Pragma("unroll")                                                             \
    for (int it_ = 0; it_ < 2; ++it_) {                                           \
      int c_ = it_ * 512 + tid;                                                   \
      int row_ = c_ >> 2, ch_ = c_ & 3;                                           \
      int chL_ = ch_ ^ ((row_ >> 1) & 3);                                         \
      GLD_LDS(&(gbase)[((rowbase) + row_) * (size_t)K + kof_ + chL_ * 8],         \
              &(dst)[c_ * 8]);                                                    \
    }                                                                             \
  } while (0)

#define LOADB(bf, kk) do {                                                        \
    _Pragma("unroll")                                                             \
    for (int j_ = 0; j_ < 4; ++j_)                                                \
      bR[j_] = *(const bf16x8*)&sB[bf][kk][(wn + j_ * 16 + l16) * 32 +            \
                                           ((quad ^ rsw) * 8)];                   \
  } while (0)

#define LOADA(bf, kk, ih) do {                                                    \
    _Pragma("unroll")                                                             \
    for (int i_ = 0; i_ < 4; ++i_)                                                \
      aR[i_] = *(const bf16x8*)&sA[bf][kk][(wm + ((ih) * 4 + i_) * 16 + l16) * 32 \
                                           + ((quad ^ rsw) * 8)];                 \
  } while (0)

#define MFMA16(ih) do {                                                           \
    __builtin_amdgcn_s_setprio(1);                                                \
    _Pragma("unroll")                                                             \
    for (int i_ = 0; i_ < 4; ++i_)                                                \
      _Pragma("unroll")                                                           \
      for (int j_ = 0; j_ < 4; ++j_)                                              \
        acc[(ih) * 4 + i_][j_] = __builtin_amdgcn_mfma_f32_16x16x32_bf16(         \
            aR[i_], bR[j_], acc[(ih) * 4 + i_][j_], 0, 0, 0);                     \
    __builtin_amdgcn_s_setprio(0);                                                \
  } while (0)

#define BAR() __builtin_amdgcn_s_barrier()
#define VMCNT4() asm volatile("s_waitcnt vmcnt(4)" ::: "memory")

  // Prologue: tile0 (4 halves) + k0(tile1); drain tile0, leave k0(1) in flight.
  STAGE(A,  bm, 0, 0, sA[0][0]);
  STAGE(Bt, bn, 0, 0, sB[0][0]);
  STAGE(A,  bm, 0, 1, sA[0][1]);
  STAGE(Bt, bn, 0, 1, sB[0][1]);
  STAGE(A,  bm, 1, 0, sA[1][0]);
  STAGE(Bt, bn, 1, 0, sB[1][0]);
  VMCNT4();
  BAR();

  for (int u = 0; u < (NT >> 1); ++u) {
    const int t0 = 2 * u;
    // ---- phase 0: tile t0 kk0, i 0-3 (+ all B kk0) ----
    LOADB(0, 0); LOADA(0, 0, 0);
    STAGE(A, bm, t0 + 1, 1, sA[1][1]);
    BAR();
    MFMA16(0);
    BAR();
    // ---- phase 1: tile t0 kk0, i 4-7 ----
    LOADA(0, 0, 1);
    STAGE(Bt, bn, t0 + 1, 1, sB[1][1]);
    BAR();
    MFMA16(1);
    BAR();
    // ---- phase 2: tile t0 kk1, i 0-3 (+ all B kk1) ----
    LOADB(0, 1); LOADA(0, 1, 0);
    STAGE(A, bm, t0 + 2, 0, sA[0][0]);
    BAR();
    MFMA16(0);
    BAR();
    // ---- phase 3: tile t0 kk1, i 4-7 ; drain tile t0+1 ----
    LOADA(0, 1, 1);
    STAGE(Bt, bn, t0 + 2, 0, sB[0][0]);
    BAR();
    MFMA16(1);
    VMCNT4();
    BAR();
    // ---- phase 4: tile t0+1 kk0, i 0-3 ----
    LOADB(1, 0); LOADA(1, 0, 0);
    STAGE(A, bm, t0 + 2, 1, sA[0][1]);
    BAR();
    MFMA16(0);
    BAR();
    // ---- phase 5: tile t0+1 kk0, i 4-7 ----
    LOADA(1, 0, 1);
    STAGE(Bt, bn, t0 + 2, 1, sB[0][1]);
    BAR();
    MFMA16(1);
    BAR();
    // ---- phase 6: tile t0+1 kk1, i 0-3 ----
    LOADB(1, 1); LOADA(1, 1, 0);
    STAGE(A, bm, t0 + 3, 0, sA[1][0]);
    BAR();
    MFMA16(0);
    BAR();
    // ---- phase 7: tile t0+1 kk1, i 4-7 ; drain tile t0+2 ----
    LOADA(1, 1, 1);
    STAGE(Bt, bn, t0 + 3, 0, sB[1][0]);
    BAR();
    MFMA16(1);
    VMCNT4();
    BAR();
  }

  // Drain remaining LDS-DMA before epilogue / endpgm (tail stages are dead data).
  asm volatile("s_waitcnt vmcnt(0)" ::: "memory");

  #pragma unroll
  for (int i = 0; i < 8; ++i)
    #pragma unroll
    for (int j = 0; j < 4; ++j)
      #pragma unroll
      for (int r = 0; r < 4; ++r) {
        size_t row = bm + wm + i * 16 + quad * 4 + r;
        size_t col = bn + wn + j * 16 + l16;
        C[row * (size_t)N + col] = (OutT)acc[i][j][r];
      }

#undef STAGE
#undef LOADB
#undef LOADA
#undef MFMA16
#undef BAR
#undef VMCNT4
}

// ---------- flash attention v3 (causal, GQA) ----------
__global__ __launch_bounds__(256, 4) void attn_kernel(const __bf16* __restrict__ Qr,
                                                      const __bf16* __restrict__ Kr,
                                                      const __bf16* __restrict__ Vt,
                                                      __bf16* __restrict__ O) {
  __shared__ __align__(16) char smem[40960];
  __bf16* Ks = (__bf16*)smem;              // [64 key][128 d], 16B chunks swizzled
  __bf16* Vs = (__bf16*)(smem + 16384);    // [128 d][64 key], swizzled
  __bf16* Ps = (__bf16*)(smem + 32768);    // [4 wave][16 q][64 key], swizzled

  const int bid = blockIdx.x;
  const int h = bid & (NH - 1);
  const int qb = (S_LEN / 64 - 1) - (bid >> 5);     // longest first
  const int kvh = h >> 2;                            // REP = 4
  const int tid = threadIdx.x;
  const int lane = tid & 63, wave = tid >> 6;
  const int quad = lane >> 4, l16 = lane & 15;
  const int sw = l16 & 7;                            // swizzle key
  const int q0 = qb * 64;

  bf16x8 qf[4];
  {
    const __bf16* qp = Qr + (size_t)(q0 + wave * 16 + l16) * (NH * HD) + (size_t)h * HD + quad * 8;
    for (int kk = 0; kk < 4; ++kk) qf[kk] = *(const bf16x8*)(qp + kk * 32);
  }
  f32x4 oacc[8] = {};
  float m2 = -INFINITY, l_i = 0.0f;
  const float C2 = SCALE_F * 1.4426950408889634f;

  for (int kb = 0; kb <= q0; kb += 64) {
    for (int pass = 0; pass < 4; ++pass) {
      int c = pass * 256 + tid;
      int row = c >> 4, ch = c & 15;
      int chs = ch ^ (row & 7);
      *(uint4*)&Ks[row * 128 + chs * 8] =
        *(const uint4*)&Kr[(size_t)(kb + row) * (NKV * HD) + (size_t)kvh * HD + ch * 8];
    }
    for (int pass = 0; pass < 4; ++pass) {
      int c = pass * 256 + tid;
      int d = c >> 3, ch = c & 7;
      int chs = ch ^ (d & 7);
      *(uint4*)&Vs[d * 64 + chs * 8] =
        *(const uint4*)&Vt[((size_t)kvh * HD + d) * S_LEN + kb + ch * 8];
    }
    __syncthreads();

    f32x4 sc[4] = {};
    for (int jt = 0; jt < 4; ++jt)
      for (int kk = 0; kk < 4; ++kk) {
        bf16x8 kf = *(const bf16x8*)&Ks[(jt * 16 + l16) * 128 + ((kk * 4 + quad) ^ sw) * 8];
        sc[jt] = __builtin_amdgcn_mfma_f32_16x16x32_bf16(kf, qf[kk], sc[jt], 0, 0, 0);
      }

    float s[16];
    for (int jt = 0; jt < 4; ++jt)
      for (int r = 0; r < 4; ++r) s[jt * 4 + r] = sc[jt][r];
    if (kb == q0) {
      int qloc = wave * 16 + l16;
      for (int jt = 0; jt < 4; ++jt)
        for (int r = 0; r < 4; ++r)
          if (jt * 16 + quad * 4 + r > qloc) s[jt * 4 + r] = -INFINITY;
    }
    float mx = s[0];
    for (int i = 1; i < 16; ++i) mx = fmaxf(mx, s[i]);
    mx = fmaxf(mx, __shfl_xor(mx, 16, 64));
    mx = fmaxf(mx, __shfl_xor(mx, 32, 64));
    float m2new = fmaxf(m2, mx * C2);
    float alpha = exp2f(m2 - m2new);
    float pv[16], sum = 0.0f;
    for (int i = 0; i < 16; ++i) { pv[i] = exp2f(fmaf(s[i], C2, -m2new)); sum += pv[i]; }
    sum += __shfl_xor(sum, 16, 64);
    sum += __shfl_xor(sum, 32, 64);
    l_i = l_i * alpha + sum;
    m2 = m2new;
    for (int dt = 0; dt < 8; ++dt) oacc[dt] *= alpha;

    __bf16* pw = Ps + wave * 1024 + l16 * 64;
    for (int jt = 0; jt < 4; ++jt) {
      bf16x4 pk = { (__bf16)pv[jt*4+0], (__bf16)pv[jt*4+1], (__bf16)pv[jt*4+2], (__bf16)pv[jt*4+3] };
      int chunk = jt * 2 + (quad >> 1);
      *(bf16x4*)&pw[((chunk ^ sw) * 8) + (quad & 1) * 4] = pk;
    }
    for (int half = 0; half < 2; ++half) {
      bf16x8 pf = *(const bf16x8*)&pw[((half * 4 + quad) ^ sw) * 8];
      for (int dt = 0; dt < 8; ++dt) {
        bf16x8 vf = *(const bf16x8*)&Vs[(dt * 16 + l16) * 64 + ((half * 4 + quad) ^ sw) * 8];
        oacc[dt] = __builtin_amdgcn_mfma_f32_16x16x32_bf16(vf, pf, oacc[dt], 0, 0, 0);
      }
    }
    __syncthreads();
  }

  float* scr = (float*)smem + wave * 2112;
  float inv = 1.0f / l_i;
  for (int dt = 0; dt < 8; ++dt) {
    f32x4 v = oacc[dt] * inv;
    *(f32x4*)&scr[l16 * 132 + dt * 16 + quad * 4] = v;
  }
  for (int it = 0; it < 4; ++it) {
    int c = it * 64 + lane;
    int row = c >> 4, ch = c & 15;
    const float* sp = &scr[row * 132 + ch * 8];
    f32x4 a = *(const f32x4*)sp;
    f32x4 b = *(const f32x4*)(sp + 4);
    bf16x8 o = { (__bf16)a[0], (__bf16)a[1], (__bf16)a[2], (__bf16)a[3],
                 (__bf16)b[0], (__bf16)b[1], (__bf16)b[2], (__bf16)b[3] };
    *(bf16x8*)&O[(size_t)(q0 + wave * 16 + row) * (NH * HD) + (size_t)h * HD + ch * 8] = o;
  }
}

extern "C" void kernel_launch(void* const* d_in, const int* in_sizes, int n_in,
                              void* d_out, int out_size, void* d_ws, size_t ws_size,
                              hipStream_t stream) {
  const float* hidden    = (const float*)d_in[0];
  const int*   positions = (const int*)d_in[1];
  const float* Wqkv      = (const float*)d_in[2];
  const float* Wo        = (const float*)d_in[3];
  float* out = (float*)d_out;

  char* p = (char*)d_ws;
  auto alloc = [&](size_t bytes) { char* r = p; p += (bytes + 255) & ~(size_t)255; return r; };
  __bf16* hid_bf = (__bf16*)alloc((size_t)S_LEN * HID * 2);       // 16 MB (reused as attn_out)
  __bf16* wqkvT  = (__bf16*)alloc((size_t)QKV_N * HID * 2);       // 48 MB  [6144][4096]
  __bf16* woT    = (__bf16*)alloc((size_t)HID * HID * 2);         // 32 MB  [4096][4096]
  __bf16* qkv    = (__bf16*)alloc((size_t)S_LEN * QKV_N * 2);     // 24 MB
  __bf16* Qr     = (__bf16*)alloc((size_t)S_LEN * NH * HD * 2);   // 16 MB
  __bf16* Kr     = (__bf16*)alloc((size_t)S_LEN * NKV * HD * 2);  // 4 MB
  __bf16* Vt     = (__bf16*)alloc((size_t)S_LEN * NKV * HD * 2);  // 4 MB
  __bf16* attn   = hid_bf;  // hidden_bf16 dead after GEMM1

  {
    int n4 = S_LEN * HID / 4;
    cast_bf16_kernel<<<(n4 + 255) / 256, 256, 0, stream>>>((const float4*)hidden, hid_bf, n4);
  }
  transpose_cast_kernel<<<dim3(QKV_N / 32, HID / 32), dim3(32, 8), 0, stream>>>(Wqkv, wqkvT, HID, QKV_N);
  transpose_cast_kernel<<<dim3(HID / 32, HID / 32), dim3(32, 8), 0, stream>>>(Wo, woT, HID, HID);
  gemm8p_kernel<__bf16><<<dim3(QKV_N / 256, S_LEN / 256), 512, 0, stream>>>(
      hid_bf, wqkvT, qkv, S_LEN, QKV_N, HID);
  {
    int total = S_LEN * NQK * 64;
    rope_kernel<<<total / 256, 256, 0, stream>>>(qkv, positions, Qr, Kr);
  }
  transpose_v_kernel<<<dim3(S_LEN / 32, HD / 32, NKV), dim3(32, 8), 0, stream>>>(qkv, Vt);
  attn_kernel<<<NH * (S_LEN / 64), 256, 0, stream>>>(Qr, Kr, Vt, attn);
  gemm8p_kernel<float><<<dim3(HID / 256, S_LEN / 256), 512, 0, stream>>>(
      attn, woT, out, S_LEN, HID, HID);
}

// Round 2
// 560.938 us; speedup vs baseline: 1.1132x; 1.1000x over previous
//
#include <hip/hip_runtime.h>
#include <math.h>

// Problem constants
#define S_LEN 2048
#define HID 4096
#define NH 32
#define NKV 8
#define HD 128
#define QKV_N ((NH + 2*NKV) * HD)   // 6144
#define NQK (NH + NKV)              // 40
static __device__ __constant__ const float SCALE_F = 0.08838834764831845f; // 128^-0.5

typedef __bf16 bf16x8 __attribute__((ext_vector_type(8)));
typedef __bf16 bf16x4 __attribute__((ext_vector_type(4)));
typedef float  f32x4  __attribute__((ext_vector_type(4)));

#define GLD_LDS(gptr, lptr) \
  __builtin_amdgcn_global_load_lds( \
      (const __attribute__((address_space(1))) uint32_t*)(gptr), \
      (__attribute__((address_space(3))) uint32_t*)(lptr), 16, 0, 0)

// ---------- cast fp32 -> bf16 (vectorized) ----------
__global__ void cast_bf16_kernel(const float4* __restrict__ in, __bf16* __restrict__ out, int n4) {
  int i = blockIdx.x * blockDim.x + threadIdx.x;
  if (i >= n4) return;
  float4 v = in[i];
  bf16x4 o = { (__bf16)v.x, (__bf16)v.y, (__bf16)v.z, (__bf16)v.w };
  *(bf16x4*)(out + (size_t)i * 4) = o;
}

// ---------- transpose + cast: in[R][C] fp32 -> out[C][R] bf16 ----------
__global__ void transpose_cast_kernel(const float* __restrict__ in, __bf16* __restrict__ out,
                                      int R, int C) {
  __shared__ float tile[32][33];
  int bx = blockIdx.x * 32;  // col of in
  int by = blockIdx.y * 32;  // row of in
  int tx = threadIdx.x, ty = threadIdx.y;
  for (int i = 0; i < 32; i += 8)
    tile[ty + i][tx] = in[(size_t)(by + ty + i) * C + bx + tx];
  __syncthreads();
  for (int i = 0; i < 32; i += 8)
    out[(size_t)(bx + ty + i) * R + by + tx] = (__bf16)tile[tx][ty + i];
}

// ---------- V transpose: Vt[kvh][d][s] = qkv[s][(NH+NKV)*HD + kvh*HD + d] ----------
__global__ void transpose_v_kernel(const __bf16* __restrict__ qkv, __bf16* __restrict__ Vt) {
  __shared__ __bf16 tile[32][33];
  int kvh = blockIdx.z;
  int sb = blockIdx.x * 32;
  int db = blockIdx.y * 32;
  int tx = threadIdx.x, ty = threadIdx.y;
  const __bf16* src = qkv + (size_t)(NH + NKV) * HD + (size_t)kvh * HD;
  for (int i = 0; i < 32; i += 8)
    tile[ty + i][tx] = src[(size_t)(sb + ty + i) * QKV_N + db + tx];
  __syncthreads();
  for (int i = 0; i < 32; i += 8)
    Vt[((size_t)kvh * HD + db + ty + i) * S_LEN + sb + tx] = tile[tx][ty + i];
}

// ---------- RoPE: split qkv -> Qr [S][NH][HD], Kr [S][NKV][HD] with rotation ----------
__global__ void rope_kernel(const __bf16* __restrict__ qkv, const int* __restrict__ pos,
                            __bf16* __restrict__ Qr, __bf16* __restrict__ Kr) {
  int idx = blockIdx.x * blockDim.x + threadIdx.x;
  int half = idx & 63;         // 0..63
  int t = idx >> 6;
  int hh = t % NQK;
  int s = t / NQK;
  if (s >= S_LEN) return;
  float p = (float)pos[s];
  float inv_freq = exp2f((float)half * -0.2076205059304601f);
  float ang = p * inv_freq;
  float cs = cosf(ang), sn = sinf(ang);
  const __bf16* src; __bf16* dst;
  if (hh < NH) {
    src = qkv + (size_t)s * QKV_N + (size_t)hh * HD;
    dst = Qr + ((size_t)s * NH + hh) * HD;
  } else {
    int kh = hh - NH;
    src = qkv + (size_t)s * QKV_N + (size_t)NH * HD + (size_t)kh * HD;
    dst = Kr + ((size_t)s * NKV + kh) * HD;
  }
  float x1 = (float)src[half], x2 = (float)src[half + 64];
  dst[half]      = (__bf16)(x1 * cs - x2 * sn);
  dst[half + 64] = (__bf16)(x2 * cs + x1 * sn);
}

// ===================================================================================
// 256x256-tile 8-phase bf16 GEMM (unchanged from R0 — see comments there).
// ===================================================================================
template <typename OutT>
__global__ __launch_bounds__(512, 2) void gemm8p_kernel(const __bf16* __restrict__ A,
                                                        const __bf16* __restrict__ Bt,
                                                        OutT* __restrict__ C,
                                                        int M, int N, int K) {
  __shared__ __align__(16) __bf16 sA[2][2][256 * 32];
  __shared__ __align__(16) __bf16 sB[2][2][256 * 32];
  const int tid = threadIdx.x;
  const int lane = tid & 63;
  const int wave = tid >> 6;
  const int quad = lane >> 4;
  const int l16 = lane & 15;
  const int wm = (wave >> 2) * 128;   // 2 M-warps
  const int wn = (wave & 3) * 64;     // 4 N-warps
  const size_t bm = (size_t)blockIdx.y * 256;
  const size_t bn = (size_t)blockIdx.x * 256;
  const int NT = K >> 6;              // K-tiles of 64
  const int rsw = (l16 >> 1) & 3;     // read-side chunk swizzle

  f32x4 acc[8][4] = {};
  bf16x8 aR[4], bR[4];

#define STAGE(gbase, rowbase, tau, h, dst) do {                                   \
    size_t kof_ = (size_t)((tau) % NT) * 64 + (h) * 32;                           \
    _Pragma("unroll")                                                             \
    for (int it_ = 0; it_ < 2; ++it_) {                                           \
      int c_ = it_ * 512 + tid;                                                   \
      int row_ = c_ >> 2, ch_ = c_ & 3;                                           \
      int chL_ = ch_ ^ ((row_ >> 1) & 3);                                         \
      GLD_LDS(&(gbase)[((rowbase) + row_) * (size_t)K + kof_ + chL_ * 8],         \
              &(dst)[c_ * 8]);                                                    \
    }                                                                             \
  } while (0)

#define LOADB(bf, kk) do {                                                        \
    _Pragma("unroll")                                                             \
    for (int j_ = 0; j_ < 4; ++j_)                                                \
      bR[j_] = *(const bf16x8*)&sB[bf][kk][(wn + j_ * 16 + l16) * 32 +            \
                                           ((quad ^ rsw) * 8)];                   \
  } while (0)

#define LOADA(bf, kk, ih) do {                                                    \
    _Pragma("unroll")                                                             \
    for (int i_ = 0; i_ < 4; ++i_)                                                \
      aR[i_] = *(const bf16x8*)&sA[bf][kk][(wm + ((ih) * 4 + i_) * 16 + l16) * 32 \
                                           + ((quad ^ rsw) * 8)];                 \
  } while (0)

#define MFMA16(ih) do {                                                           \
    __builtin_amdgcn_s_setprio(1);                                                \
    _Pragma("unroll")                                                             \
    for (int i_ = 0; i_ < 4; ++i_)                                                \
      _Pragma("unroll")                                                           \
      for (int j_ = 0; j_ < 4; ++j_)                                              \
        acc[(ih) * 4 + i_][j_] = __builtin_amdgcn_mfma_f32_16x16x32_bf16(         \
            aR[i_], bR[j_], acc[(ih) * 4 + i_][j_], 0, 0, 0);                     \
    __builtin_amdgcn_s_setprio(0);                                                \
  } while (0)

#define BAR() __builtin_amdgcn_s_barrier()
#define VMCNT4() asm volatile("s_waitcnt vmcnt(4)" ::: "memory")

  STAGE(A,  bm, 0, 0, sA[0][0]);
  STAGE(Bt, bn, 0, 0, sB[0][0]);
  STAGE(A,  bm, 0, 1, sA[0][1]);
  STAGE(Bt, bn, 0, 1, sB[0][1]);
  STAGE(A,  bm, 1, 0, sA[1][0]);
  STAGE(Bt, bn, 1, 0, sB[1][0]);
  VMCNT4();
  BAR();

  for (int u = 0; u < (NT >> 1); ++u) {
    const int t0 = 2 * u;
    LOADB(0, 0); LOADA(0, 0, 0);
    STAGE(A, bm, t0 + 1, 1, sA[1][1]);
    BAR();
    MFMA16(0);
    BAR();
    LOADA(0, 0, 1);
    STAGE(Bt, bn, t0 + 1, 1, sB[1][1]);
    BAR();
    MFMA16(1);
    BAR();
    LOADB(0, 1); LOADA(0, 1, 0);
    STAGE(A, bm, t0 + 2, 0, sA[0][0]);
    BAR();
    MFMA16(0);
    BAR();
    LOADA(0, 1, 1);
    STAGE(Bt, bn, t0 + 2, 0, sB[0][0]);
    BAR();
    MFMA16(1);
    VMCNT4();
    BAR();
    LOADB(1, 0); LOADA(1, 0, 0);
    STAGE(A, bm, t0 + 2, 1, sA[0][1]);
    BAR();
    MFMA16(0);
    BAR();
    LOADA(1, 0, 1);
    STAGE(Bt, bn, t0 + 2, 1, sB[0][1]);
    BAR();
    MFMA16(1);
    BAR();
    LOADB(1, 1); LOADA(1, 1, 0);
    STAGE(A, bm, t0 + 3, 0, sA[1][0]);
    BAR();
    MFMA16(0);
    BAR();
    LOADA(1, 1, 1);
    STAGE(Bt, bn, t0 + 3, 0, sB[1][0]);
    BAR();
    MFMA16(1);
    VMCNT4();
    BAR();
  }

  asm volatile("s_waitcnt vmcnt(0)" ::: "memory");

  #pragma unroll
  for (int i = 0; i < 8; ++i)
    #pragma unroll
    for (int j = 0; j < 4; ++j)
      #pragma unroll
      for (int r = 0; r < 4; ++r) {
        size_t row = bm + wm + i * 16 + quad * 4 + r;
        size_t col = bn + wn + j * 16 + l16;
        C[row * (size_t)N + col] = (OutT)acc[i][j][r];
      }

#undef STAGE
#undef LOADB
#undef LOADA
#undef MFMA16
#undef BAR
#undef VMCNT4
}

// ---------- flash attention v3 (causal, GQA) — 2-phase pipelined staging ----------
// R1 change: double-buffered K/V in LDS, staged via global_load_lds with the XOR
// swizzle moved to the GLOBAL source address (G21: gload_lds writes linearly, so
// LDS(row,ch) holds global chunk ch^(row&7) — identical to the old reg-staged
// layout; all read-side swizzles unchanged). Next tile's stage issues right after
// the tile barrier and its HBM/L2 latency hides under QK+softmax+PV; the single
// __syncthreads() per tile (vmcnt(0)+barrier) drains it. One barrier/tile vs two.
// T5: setprio(1) around both MFMA clusters (independent blocks -> arbitration pays).
// LDS: 2x16K (K) + 2x16K (V) + 8K (Ps) = 72 KiB -> 2 blocks/CU.
__global__ __launch_bounds__(256, 2) void attn_kernel(const __bf16* __restrict__ Qr,
                                                      const __bf16* __restrict__ Kr,
                                                      const __bf16* __restrict__ Vt,
                                                      __bf16* __restrict__ O) {
  __shared__ __align__(16) char smem[73728];
  // [buf][64 key][128 d] at smem + buf*16384 ; [buf][128 d][64 key] at smem+32768+buf*16384
  __bf16* Ps = (__bf16*)(smem + 65536);    // [4 wave][16 q][64 key], swizzled

  const int bid = blockIdx.x;
  const int h = bid & (NH - 1);
  const int qb = (S_LEN / 64 - 1) - (bid >> 5);     // longest first
  const int kvh = h >> 2;                            // REP = 4
  const int tid = threadIdx.x;
  const int lane = tid & 63, wave = tid >> 6;
  const int quad = lane >> 4, l16 = lane & 15;
  const int sw = l16 & 7;                            // swizzle key
  const int q0 = qb * 64;

  // K: 1024 x 16B chunks; dest linear in c, source chunk pre-swizzled ch^(row&7).
  // V: 1024 x 16B chunks; dest linear in c, source chunk pre-swizzled ch^(d&7).
#define STAGE_KV(kbase, bufv) do {                                                 \
    char* kd_ = smem + (bufv) * 16384;                                             \
    char* vd_ = smem + 32768 + (bufv) * 16384;                                     \
    _Pragma("unroll")                                                              \
    for (int pass_ = 0; pass_ < 4; ++pass_) {                                      \
      int c_ = pass_ * 256 + tid;                                                  \
      int row_ = c_ >> 4, ch_ = c_ & 15;                                           \
      int chs_ = ch_ ^ (row_ & 7);                                                 \
      GLD_LDS(&Kr[(size_t)((kbase) + row_) * (NKV * HD) + (size_t)kvh * HD + chs_ * 8], \
              kd_ + c_ * 16);                                                      \
    }                                                                              \
    _Pragma("unroll")                                                              \
    for (int pass_ = 0; pass_ < 4; ++pass_) {                                      \
      int c_ = pass_ * 256 + tid;                                                  \
      int d_ = c_ >> 3, ch_ = c_ & 7;                                              \
      int chs_ = ch_ ^ (d_ & 7);                                                   \
      GLD_LDS(&Vt[((size_t)kvh * HD + d_) * S_LEN + (kbase) + chs_ * 8],           \
              vd_ + c_ * 16);                                                      \
    }                                                                              \
  } while (0)

  bf16x8 qf[4];
  {
    const __bf16* qp = Qr + (size_t)(q0 + wave * 16 + l16) * (NH * HD) + (size_t)h * HD + quad * 8;
    for (int kk = 0; kk < 4; ++kk) qf[kk] = *(const bf16x8*)(qp + kk * 32);
  }
  f32x4 oacc[8] = {};
  float m2 = -INFINITY, l_i = 0.0f;
  const float C2 = SCALE_F * 1.4426950408889634f;

  int buf = 0;
  STAGE_KV(0, 0);
  for (int kb = 0; kb <= q0; kb += 64) {
    // vmcnt(0)+barrier: current buf's DMA complete; all waves done reading buf^1
    __syncthreads();
    if (kb + 64 <= q0) STAGE_KV(kb + 64, buf ^ 1);   // uniform branch; hides under compute

    const __bf16* Ks = (const __bf16*)(smem + buf * 16384);
    const __bf16* Vs = (const __bf16*)(smem + 32768 + buf * 16384);

    f32x4 sc[4] = {};
    __builtin_amdgcn_s_setprio(1);
    for (int jt = 0; jt < 4; ++jt)
      for (int kk = 0; kk < 4; ++kk) {
        bf16x8 kf = *(const bf16x8*)&Ks[(jt * 16 + l16) * 128 + ((kk * 4 + quad) ^ sw) * 8];
        sc[jt] = __builtin_amdgcn_mfma_f32_16x16x32_bf16(kf, qf[kk], sc[jt], 0, 0, 0);
      }
    __builtin_amdgcn_s_setprio(0);

    float s[16];
    for (int jt = 0; jt < 4; ++jt)
      for (int r = 0; r < 4; ++r) s[jt * 4 + r] = sc[jt][r];
    if (kb == q0) {
      int qloc = wave * 16 + l16;
      for (int jt = 0; jt < 4; ++jt)
        for (int r = 0; r < 4; ++r)
          if (jt * 16 + quad * 4 + r > qloc) s[jt * 4 + r] = -INFINITY;
    }
    float mx = s[0];
    for (int i = 1; i < 16; ++i) mx = fmaxf(mx, s[i]);
    mx = fmaxf(mx, __shfl_xor(mx, 16, 64));
    mx = fmaxf(mx, __shfl_xor(mx, 32, 64));
    float m2new = fmaxf(m2, mx * C2);
    float alpha = exp2f(m2 - m2new);
    float pv[16], sum = 0.0f;
    for (int i = 0; i < 16; ++i) { pv[i] = exp2f(fmaf(s[i], C2, -m2new)); sum += pv[i]; }
    sum += __shfl_xor(sum, 16, 64);
    sum += __shfl_xor(sum, 32, 64);
    l_i = l_i * alpha + sum;
    m2 = m2new;
    for (int dt = 0; dt < 8; ++dt) oacc[dt] *= alpha;

    __bf16* pw = Ps + wave * 1024 + l16 * 64;
    for (int jt = 0; jt < 4; ++jt) {
      bf16x4 pk = { (__bf16)pv[jt*4+0], (__bf16)pv[jt*4+1], (__bf16)pv[jt*4+2], (__bf16)pv[jt*4+3] };
      int chunk = jt * 2 + (quad >> 1);
      *(bf16x4*)&pw[((chunk ^ sw) * 8) + (quad & 1) * 4] = pk;
    }
    // no barrier: wave reads only its own Ps slice (LDS in-order per wave)
    __builtin_amdgcn_s_setprio(1);
    for (int half = 0; half < 2; ++half) {
      bf16x8 pf = *(const bf16x8*)&pw[((half * 4 + quad) ^ sw) * 8];
      for (int dt = 0; dt < 8; ++dt) {
        bf16x8 vf = *(const bf16x8*)&Vs[(dt * 16 + l16) * 64 + ((half * 4 + quad) ^ sw) * 8];
        oacc[dt] = __builtin_amdgcn_mfma_f32_16x16x32_bf16(vf, pf, oacc[dt], 0, 0, 0);
      }
    }
    __builtin_amdgcn_s_setprio(0);
    buf ^= 1;
  }
  __syncthreads();   // all waves done with K/V before scratch reuse; no DMA in flight

#undef STAGE_KV

  float* scr = (float*)smem + wave * 2112;
  float inv = 1.0f / l_i;
  for (int dt = 0; dt < 8; ++dt) {
    f32x4 v = oacc[dt] * inv;
    *(f32x4*)&scr[l16 * 132 + dt * 16 + quad * 4] = v;
  }
  for (int it = 0; it < 4; ++it) {
    int c = it * 64 + lane;
    int row = c >> 4, ch = c & 15;
    const float* sp = &scr[row * 132 + ch * 8];
    f32x4 a = *(const f32x4*)sp;
    f32x4 b = *(const f32x4*)(sp + 4);
    bf16x8 o = { (__bf16)a[0], (__bf16)a[1], (__bf16)a[2], (__bf16)a[3],
                 (__bf16)b[0], (__bf16)b[1], (__bf16)b[2], (__bf16)b[3] };
    *(bf16x8*)&O[(size_t)(q0 + wave * 16 + row) * (NH * HD) + (size_t)h * HD + ch * 8] = o;
  }
}

extern "C" void kernel_launch(void* const* d_in, const int* in_sizes, int n_in,
                              void* d_out, int out_size, void* d_ws, size_t ws_size,
                              hipStream_t stream) {
  const float* hidden    = (const float*)d_in[0];
  const int*   positions = (const int*)d_in[1];
  const float* Wqkv      = (const float*)d_in[2];
  const float* Wo        = (const float*)d_in[3];
  float* out = (float*)d_out;

  char* p = (char*)d_ws;
  auto alloc = [&](size_t bytes) { char* r = p; p += (bytes + 255) & ~(size_t)255; return r; };
  __bf16* hid_bf = (__bf16*)alloc((size_t)S_LEN * HID * 2);       // 16 MB (reused as attn_out)
  __bf16* wqkvT  = (__bf16*)alloc((size_t)QKV_N * HID * 2);       // 48 MB  [6144][4096]
  __bf16* woT    = (__bf16*)alloc((size_t)HID * HID * 2);         // 32 MB  [4096][4096]
  __bf16* qkv    = (__bf16*)alloc((size_t)S_LEN * QKV_N * 2);     // 24 MB
  __bf16* Qr     = (__bf16*)alloc((size_t)S_LEN * NH * HD * 2);   // 16 MB
  __bf16* Kr     = (__bf16*)alloc((size_t)S_LEN * NKV * HD * 2);  // 4 MB
  __bf16* Vt     = (__bf16*)alloc((size_t)S_LEN * NKV * HD * 2);  // 4 MB
  __bf16* attn   = hid_bf;  // hidden_bf16 dead after GEMM1

  {
    int n4 = S_LEN * HID / 4;
    cast_bf16_kernel<<<(n4 + 255) / 256, 256, 0, stream>>>((const float4*)hidden, hid_bf, n4);
  }
  transpose_cast_kernel<<<dim3(QKV_N / 32, HID / 32), dim3(32, 8), 0, stream>>>(Wqkv, wqkvT, HID, QKV_N);
  transpose_cast_kernel<<<dim3(HID / 32, HID / 32), dim3(32, 8), 0, stream>>>(Wo, woT, HID, HID);
  gemm8p_kernel<__bf16><<<dim3(QKV_N / 256, S_LEN / 256), 512, 0, stream>>>(
      hid_bf, wqkvT, qkv, S_LEN, QKV_N, HID);
  {
    int total = S_LEN * NQK * 64;
    rope_kernel<<<total / 256, 256, 0, stream>>>(qkv, positions, Qr, Kr);
  }
  transpose_v_kernel<<<dim3(S_LEN / 32, HD / 32, NKV), dim3(32, 8), 0, stream>>>(qkv, Vt);
  attn_kernel<<<NH * (S_LEN / 64), 256, 0, stream>>>(Qr, Kr, Vt, attn);
  gemm8p_kernel<float><<<dim3(HID / 256, S_LEN / 256), 512, 0, stream>>>(
      attn, woT, out, S_LEN, HID, HID);
}

// Round 3
// 539.698 us; speedup vs baseline: 1.1570x; 1.0394x over previous
//
#include <hip/hip_runtime.h>
#include <math.h>
#include <stdint.h>

// Problem constants
#define S_LEN 2048
#define HID 4096
#define NH 32
#define NKV 8
#define HD 128
#define QKV_N ((NH + 2*NKV) * HD)   // 6144
#define NQK (NH + NKV)              // 40
static __device__ __constant__ const float SCALE_F = 0.08838834764831845f; // 128^-0.5

typedef __bf16 bf16x8 __attribute__((ext_vector_type(8)));
typedef __bf16 bf16x4 __attribute__((ext_vector_type(4)));
typedef float  f32x4  __attribute__((ext_vector_type(4)));
typedef uint32_t u32x4 __attribute__((ext_vector_type(4)));

#define GLD_LDS(gptr, lptr) \
  __builtin_amdgcn_global_load_lds( \
      (const __attribute__((address_space(1))) uint32_t*)(gptr), \
      (__attribute__((address_space(3))) uint32_t*)(lptr), 16, 0, 0)

// ---------- cast fp32 -> bf16 (vectorized) ----------
__global__ void cast_bf16_kernel(const float4* __restrict__ in, __bf16* __restrict__ out, int n4) {
  int i = blockIdx.x * blockDim.x + threadIdx.x;
  if (i >= n4) return;
  float4 v = in[i];
  bf16x4 o = { (__bf16)v.x, (__bf16)v.y, (__bf16)v.z, (__bf16)v.w };
  *(bf16x4*)(out + (size_t)i * 4) = o;
}

// ---------- transpose + cast: in[R][C] fp32 -> out[C][R] bf16 ----------
__global__ void transpose_cast_kernel(const float* __restrict__ in, __bf16* __restrict__ out,
                                      int R, int C) {
  __shared__ float tile[32][33];
  int bx = blockIdx.x * 32;  // col of in
  int by = blockIdx.y * 32;  // row of in
  int tx = threadIdx.x, ty = threadIdx.y;
  for (int i = 0; i < 32; i += 8)
    tile[ty + i][tx] = in[(size_t)(by + ty + i) * C + bx + tx];
  __syncthreads();
  for (int i = 0; i < 32; i += 8)
    out[(size_t)(bx + ty + i) * R + by + tx] = (__bf16)tile[tx][ty + i];
}

// ---------- V transpose: Vt[kvh][d][s] = qkv[s][(NH+NKV)*HD + kvh*HD + d] ----------
__global__ void transpose_v_kernel(const __bf16* __restrict__ qkv, __bf16* __restrict__ Vt) {
  __shared__ __bf16 tile[32][33];
  int kvh = blockIdx.z;
  int sb = blockIdx.x * 32;
  int db = blockIdx.y * 32;
  int tx = threadIdx.x, ty = threadIdx.y;
  const __bf16* src = qkv + (size_t)(NH + NKV) * HD + (size_t)kvh * HD;
  for (int i = 0; i < 32; i += 8)
    tile[ty + i][tx] = src[(size_t)(sb + ty + i) * QKV_N + db + tx];
  __syncthreads();
  for (int i = 0; i < 32; i += 8)
    Vt[((size_t)kvh * HD + db + ty + i) * S_LEN + sb + tx] = tile[tx][ty + i];
}

// ---------- RoPE: split qkv -> Qr [S][NH][HD], Kr [S][NKV][HD] with rotation ----------
__global__ void rope_kernel(const __bf16* __restrict__ qkv, const int* __restrict__ pos,
                            __bf16* __restrict__ Qr, __bf16* __restrict__ Kr) {
  int idx = blockIdx.x * blockDim.x + threadIdx.x;
  int half = idx & 63;         // 0..63
  int t = idx >> 6;
  int hh = t % NQK;
  int s = t / NQK;
  if (s >= S_LEN) return;
  float p = (float)pos[s];
  float inv_freq = exp2f((float)half * -0.2076205059304601f);
  float ang = p * inv_freq;
  float cs = cosf(ang), sn = sinf(ang);
  const __bf16* src; __bf16* dst;
  if (hh < NH) {
    src = qkv + (size_t)s * QKV_N + (size_t)hh * HD;
    dst = Qr + ((size_t)s * NH + hh) * HD;
  } else {
    int kh = hh - NH;
    src = qkv + (size_t)s * QKV_N + (size_t)NH * HD + (size_t)kh * HD;
    dst = Kr + ((size_t)s * NKV + kh) * HD;
  }
  float x1 = (float)src[half], x2 = (float)src[half + 64];
  dst[half]      = (__bf16)(x1 * cs - x2 * sn);
  dst[half + 64] = (__bf16)(x2 * cs + x1 * sn);
}

// ===================================================================================
// 256x256-tile 8-phase bf16 GEMM. R3 changes vs R2:
//  (1) Fragment loads are INLINE-ASM ds_read_b128 (invisible to SIInsertWaitcnts, so
//      the compiler no longer inserts conservative vmcnt waits for the LDS-DMA ->
//      ds_read hazard; ordering is carried ONLY by the explicit vmcnt(4) at phases
//      3/7 — invariants re-verified: every buffer's DMA is drained by a VMCNT4
//      before the barrier preceding its first read; every STAGE targets a buffer
//      whose last read completed >=1 barrier earlier).
//      After each phase's barrier: s_waitcnt lgkmcnt(0) + sched_barrier(0)
//      (rule #18: prevents MFMA hoisting above the wait).
//  (2) T1 bijective XCD swizzle: nwg%8==0 (192/128); each XCD gets one contiguous
//      by-row chunk -> shared A-panel (2 MB) is L2-resident.
// ===================================================================================
template <typename OutT>
__global__ __launch_bounds__(512, 2) void gemm8p_kernel(const __bf16* __restrict__ A,
                                                        const __bf16* __restrict__ Bt,
                                                        OutT* __restrict__ C,
                                                        int M, int N, int K) {
  __shared__ __align__(16) __bf16 sA[2][2][256 * 32];
  __shared__ __align__(16) __bf16 sB[2][2][256 * 32];
  const int tid = threadIdx.x;
  const int lane = tid & 63;
  const int wave = tid >> 6;
  const int quad = lane >> 4;
  const int l16 = lane & 15;
  const int wm = (wave >> 2) * 128;   // 2 M-warps
  const int wn = (wave & 3) * 64;     // 4 N-warps

  // T1: bijective XCD swizzle (requires nwg % 8 == 0; true for 192 and 128)
  const int nx = gridDim.x;
  const int nwg = nx * gridDim.y;
  int bid = blockIdx.y * nx + blockIdx.x;
  int swz = (bid & 7) * (nwg >> 3) + (bid >> 3);
  const size_t bm = (size_t)(swz / nx) * 256;
  const size_t bn = (size_t)(swz % nx) * 256;

  const int NT = K >> 6;              // K-tiles of 64
  const int rsw = (l16 >> 1) & 3;     // read-side chunk swizzle

  f32x4 acc[8][4] = {};
  bf16x8 aR[4], bR[4];

  // LDS byte addresses for inline-asm ds_read (AS3 pointer value == LDS offset)
  typedef __attribute__((address_space(3))) __bf16 lds_bf16;
  const uint32_t sAb = (uint32_t)(uintptr_t)(lds_bf16*)&sA[0][0][0];
  const uint32_t sBb = (uint32_t)(uintptr_t)(lds_bf16*)&sB[0][0][0];
  const uint32_t aBase = sAb + (uint32_t)(((wm + l16) * 32 + (quad ^ rsw) * 8) * 2);
  const uint32_t bBase = sBb + (uint32_t)(((wn + l16) * 32 + (quad ^ rsw) * 8) * 2);
  // strides (bytes): buf = 32768, khalf = 16384, 16-row fragment = 1024, ih = 4096

#define DSRD4(dst, baseaddr) do {                                                 \
    u32x4 t0_, t1_, t2_, t3_;                                                     \
    asm volatile("ds_read_b128 %0, %4\n\t"                                        \
                 "ds_read_b128 %1, %4 offset:1024\n\t"                            \
                 "ds_read_b128 %2, %4 offset:2048\n\t"                            \
                 "ds_read_b128 %3, %4 offset:3072"                                \
                 : "=&v"(t0_), "=&v"(t1_), "=&v"(t2_), "=&v"(t3_)                 \
                 : "v"(baseaddr));                                                \
    dst[0] = __builtin_bit_cast(bf16x8, t0_);                                     \
    dst[1] = __builtin_bit_cast(bf16x8, t1_);                                     \
    dst[2] = __builtin_bit_cast(bf16x8, t2_);                                     \
    dst[3] = __builtin_bit_cast(bf16x8, t3_);                                     \
  } while (0)

#define LOADB(bf, kk) DSRD4(bR, bBase + (bf) * 32768u + (kk) * 16384u)
#define LOADA(bf, kk, ih) DSRD4(aR, aBase + (bf) * 32768u + (kk) * 16384u + (ih) * 4096u)

#define STAGE(gbase, rowbase, tau, h, dst) do {                                   \
    size_t kof_ = (size_t)((tau) % NT) * 64 + (h) * 32;                           \
    _Pragma("unroll")                                                             \
    for (int it_ = 0; it_ < 2; ++it_) {                                           \
      int c_ = it_ * 512 + tid;                                                   \
      int row_ = c_ >> 2, ch_ = c_ & 3;                                           \
      int chL_ = ch_ ^ ((row_ >> 1) & 3);                                         \
      GLD_LDS(&(gbase)[((rowbase) + row_) * (size_t)K + kof_ + chL_ * 8],         \
              &(dst)[c_ * 8]);                                                    \
    }                                                                             \
  } while (0)

#define MFMA16(ih) do {                                                           \
    __builtin_amdgcn_s_setprio(1);                                                \
    _Pragma("unroll")                                                             \
    for (int i_ = 0; i_ < 4; ++i_)                                                \
      _Pragma("unroll")                                                           \
      for (int j_ = 0; j_ < 4; ++j_)                                              \
        acc[(ih) * 4 + i_][j_] = __builtin_amdgcn_mfma_f32_16x16x32_bf16(         \
            aR[i_], bR[j_], acc[(ih) * 4 + i_][j_], 0, 0, 0);                     \
    __builtin_amdgcn_s_setprio(0);                                                \
    __builtin_amdgcn_sched_barrier(0);                                            \
  } while (0)

#define BAR() __builtin_amdgcn_s_barrier()
#define LGKM0() do { asm volatile("s_waitcnt lgkmcnt(0)");                        \
                     __builtin_amdgcn_sched_barrier(0); } while (0)
#define VMCNT4() asm volatile("s_waitcnt vmcnt(4)" ::: "memory")

  // Prologue: tile0 (4 halves) + k0(tile1); drain tile0, leave k0(1) in flight.
  STAGE(A,  bm, 0, 0, sA[0][0]);
  STAGE(Bt, bn, 0, 0, sB[0][0]);
  STAGE(A,  bm, 0, 1, sA[0][1]);
  STAGE(Bt, bn, 0, 1, sB[0][1]);
  STAGE(A,  bm, 1, 0, sA[1][0]);
  STAGE(Bt, bn, 1, 0, sB[1][0]);
  VMCNT4();
  BAR();

  for (int u = 0; u < (NT >> 1); ++u) {
    const int t0 = 2 * u;
    // ---- phase 0: tile t0 kk0, i 0-3 ----
    LOADB(0, 0); LOADA(0, 0, 0);
    STAGE(A, bm, t0 + 1, 1, sA[1][1]);
    BAR();
    LGKM0();
    MFMA16(0);
    BAR();
    // ---- phase 1: tile t0 kk0, i 4-7 ----
    LOADA(0, 0, 1);
    STAGE(Bt, bn, t0 + 1, 1, sB[1][1]);
    BAR();
    LGKM0();
    MFMA16(1);
    BAR();
    // ---- phase 2: tile t0 kk1, i 0-3 ----
    LOADB(0, 1); LOADA(0, 1, 0);
    STAGE(A, bm, t0 + 2, 0, sA[0][0]);
    BAR();
    LGKM0();
    MFMA16(0);
    BAR();
    // ---- phase 3: tile t0 kk1, i 4-7 ; drain tile t0+1 ----
    LOADA(0, 1, 1);
    STAGE(Bt, bn, t0 + 2, 0, sB[0][0]);
    BAR();
    LGKM0();
    MFMA16(1);
    VMCNT4();
    BAR();
    // ---- phase 4: tile t0+1 kk0, i 0-3 ----
    LOADB(1, 0); LOADA(1, 0, 0);
    STAGE(A, bm, t0 + 2, 1, sA[0][1]);
    BAR();
    LGKM0();
    MFMA16(0);
    BAR();
    // ---- phase 5: tile t0+1 kk0, i 4-7 ----
    LOADA(1, 0, 1);
    STAGE(Bt, bn, t0 + 2, 1, sB[0][1]);
    BAR();
    LGKM0();
    MFMA16(1);
    BAR();
    // ---- phase 6: tile t0+1 kk1, i 0-3 ----
    LOADB(1, 1); LOADA(1, 1, 0);
    STAGE(A, bm, t0 + 3, 0, sA[1][0]);
    BAR();
    LGKM0();
    MFMA16(0);
    BAR();
    // ---- phase 7: tile t0+1 kk1, i 4-7 ; drain tile t0+2 ----
    LOADA(1, 1, 1);
    STAGE(Bt, bn, t0 + 3, 0, sB[1][0]);
    BAR();
    LGKM0();
    MFMA16(1);
    VMCNT4();
    BAR();
  }

  // Drain remaining LDS-DMA before epilogue / endpgm (tail stages are dead data).
  asm volatile("s_waitcnt vmcnt(0)" ::: "memory");

  #pragma unroll
  for (int i = 0; i < 8; ++i)
    #pragma unroll
    for (int j = 0; j < 4; ++j)
      #pragma unroll
      for (int r = 0; r < 4; ++r) {
        size_t row = bm + wm + i * 16 + quad * 4 + r;
        size_t col = bn + wn + j * 16 + l16;
        C[row * (size_t)N + col] = (OutT)acc[i][j][r];
      }

#undef STAGE
#undef LOADB
#undef LOADA
#undef DSRD4
#undef MFMA16
#undef BAR
#undef LGKM0
#undef VMCNT4
}

// ---------- flash attention v3 (causal, GQA) — 2-phase pipelined staging ----------
// (unchanged from R2)
__global__ __launch_bounds__(256, 2) void attn_kernel(const __bf16* __restrict__ Qr,
                                                      const __bf16* __restrict__ Kr,
                                                      const __bf16* __restrict__ Vt,
                                                      __bf16* __restrict__ O) {
  __shared__ __align__(16) char smem[73728];
  __bf16* Ps = (__bf16*)(smem + 65536);    // [4 wave][16 q][64 key], swizzled

  const int bid = blockIdx.x;
  const int h = bid & (NH - 1);
  const int qb = (S_LEN / 64 - 1) - (bid >> 5);     // longest first
  const int kvh = h >> 2;                            // REP = 4
  const int tid = threadIdx.x;
  const int lane = tid & 63, wave = tid >> 6;
  const int quad = lane >> 4, l16 = lane & 15;
  const int sw = l16 & 7;                            // swizzle key
  const int q0 = qb * 64;

#define STAGE_KV(kbase, bufv) do {                                                 \
    char* kd_ = smem + (bufv) * 16384;                                             \
    char* vd_ = smem + 32768 + (bufv) * 16384;                                     \
    _Pragma("unroll")                                                              \
    for (int pass_ = 0; pass_ < 4; ++pass_) {                                      \
      int c_ = pass_ * 256 + tid;                                                  \
      int row_ = c_ >> 4, ch_ = c_ & 15;                                           \
      int chs_ = ch_ ^ (row_ & 7);                                                 \
      GLD_LDS(&Kr[(size_t)((kbase) + row_) * (NKV * HD) + (size_t)kvh * HD + chs_ * 8], \
              kd_ + c_ * 16);                                                      \
    }                                                                              \
    _Pragma("unroll")                                                              \
    for (int pass_ = 0; pass_ < 4; ++pass_) {                                      \
      int c_ = pass_ * 256 + tid;                                                  \
      int d_ = c_ >> 3, ch_ = c_ & 7;                                              \
      int chs_ = ch_ ^ (d_ & 7);                                                   \
      GLD_LDS(&Vt[((size_t)kvh * HD + d_) * S_LEN + (kbase) + chs_ * 8],           \
              vd_ + c_ * 16);                                                      \
    }                                                                              \
  } while (0)

  bf16x8 qf[4];
  {
    const __bf16* qp = Qr + (size_t)(q0 + wave * 16 + l16) * (NH * HD) + (size_t)h * HD + quad * 8;
    for (int kk = 0; kk < 4; ++kk) qf[kk] = *(const bf16x8*)(qp + kk * 32);
  }
  f32x4 oacc[8] = {};
  float m2 = -INFINITY, l_i = 0.0f;
  const float C2 = SCALE_F * 1.4426950408889634f;

  int buf = 0;
  STAGE_KV(0, 0);
  for (int kb = 0; kb <= q0; kb += 64) {
    __syncthreads();
    if (kb + 64 <= q0) STAGE_KV(kb + 64, buf ^ 1);

    const __bf16* Ks = (const __bf16*)(smem + buf * 16384);
    const __bf16* Vs = (const __bf16*)(smem + 32768 + buf * 16384);

    f32x4 sc[4] = {};
    __builtin_amdgcn_s_setprio(1);
    for (int jt = 0; jt < 4; ++jt)
      for (int kk = 0; kk < 4; ++kk) {
        bf16x8 kf = *(const bf16x8*)&Ks[(jt * 16 + l16) * 128 + ((kk * 4 + quad) ^ sw) * 8];
        sc[jt] = __builtin_amdgcn_mfma_f32_16x16x32_bf16(kf, qf[kk], sc[jt], 0, 0, 0);
      }
    __builtin_amdgcn_s_setprio(0);

    float s[16];
    for (int jt = 0; jt < 4; ++jt)
      for (int r = 0; r < 4; ++r) s[jt * 4 + r] = sc[jt][r];
    if (kb == q0) {
      int qloc = wave * 16 + l16;
      for (int jt = 0; jt < 4; ++jt)
        for (int r = 0; r < 4; ++r)
          if (jt * 16 + quad * 4 + r > qloc) s[jt * 4 + r] = -INFINITY;
    }
    float mx = s[0];
    for (int i = 1; i < 16; ++i) mx = fmaxf(mx, s[i]);
    mx = fmaxf(mx, __shfl_xor(mx, 16, 64));
    mx = fmaxf(mx, __shfl_xor(mx, 32, 64));
    float m2new = fmaxf(m2, mx * C2);
    float alpha = exp2f(m2 - m2new);
    float pv[16], sum = 0.0f;
    for (int i = 0; i < 16; ++i) { pv[i] = exp2f(fmaf(s[i], C2, -m2new)); sum += pv[i]; }
    sum += __shfl_xor(sum, 16, 64);
    sum += __shfl_xor(sum, 32, 64);
    l_i = l_i * alpha + sum;
    m2 = m2new;
    for (int dt = 0; dt < 8; ++dt) oacc[dt] *= alpha;

    __bf16* pw = Ps + wave * 1024 + l16 * 64;
    for (int jt = 0; jt < 4; ++jt) {
      bf16x4 pk = { (__bf16)pv[jt*4+0], (__bf16)pv[jt*4+1], (__bf16)pv[jt*4+2], (__bf16)pv[jt*4+3] };
      int chunk = jt * 2 + (quad >> 1);
      *(bf16x4*)&pw[((chunk ^ sw) * 8) + (quad & 1) * 4] = pk;
    }
    __builtin_amdgcn_s_setprio(1);
    for (int half = 0; half < 2; ++half) {
      bf16x8 pf = *(const bf16x8*)&pw[((half * 4 + quad) ^ sw) * 8];
      for (int dt = 0; dt < 8; ++dt) {
        bf16x8 vf = *(const bf16x8*)&Vs[(dt * 16 + l16) * 64 + ((half * 4 + quad) ^ sw) * 8];
        oacc[dt] = __builtin_amdgcn_mfma_f32_16x16x32_bf16(vf, pf, oacc[dt], 0, 0, 0);
      }
    }
    __builtin_amdgcn_s_setprio(0);
    buf ^= 1;
  }
  __syncthreads();

#undef STAGE_KV

  float* scr = (float*)smem + wave * 2112;
  float inv = 1.0f / l_i;
  for (int dt = 0; dt < 8; ++dt) {
    f32x4 v = oacc[dt] * inv;
    *(f32x4*)&scr[l16 * 132 + dt * 16 + quad * 4] = v;
  }
  for (int it = 0; it < 4; ++it) {
    int c = it * 64 + lane;
    int row = c >> 4, ch = c & 15;
    const float* sp = &scr[row * 132 + ch * 8];
    f32x4 a = *(const f32x4*)sp;
    f32x4 b = *(const f32x4*)(sp + 4);
    bf16x8 o = { (__bf16)a[0], (__bf16)a[1], (__bf16)a[2], (__bf16)a[3],
                 (__bf16)b[0], (__bf16)b[1], (__bf16)b[2], (__bf16)b[3] };
    *(bf16x8*)&O[(size_t)(q0 + wave * 16 + row) * (NH * HD) + (size_t)h * HD + ch * 8] = o;
  }
}

extern "C" void kernel_launch(void* const* d_in, const int* in_sizes, int n_in,
                              void* d_out, int out_size, void* d_ws, size_t ws_size,
                              hipStream_t stream) {
  const float* hidden    = (const float*)d_in[0];
  const int*   positions = (const int*)d_in[1];
  const float* Wqkv      = (const float*)d_in[2];
  const float* Wo        = (const float*)d_in[3];
  float* out = (float*)d_out;

  char* p = (char*)d_ws;
  auto alloc = [&](size_t bytes) { char* r = p; p += (bytes + 255) & ~(size_t)255; return r; };
  __bf16* hid_bf = (__bf16*)alloc((size_t)S_LEN * HID * 2);       // 16 MB (reused as attn_out)
  __bf16* wqkvT  = (__bf16*)alloc((size_t)QKV_N * HID * 2);       // 48 MB  [6144][4096]
  __bf16* woT    = (__bf16*)alloc((size_t)HID * HID * 2);         // 32 MB  [4096][4096]
  __bf16* qkv    = (__bf16*)alloc((size_t)S_LEN * QKV_N * 2);     // 24 MB
  __bf16* Qr     = (__bf16*)alloc((size_t)S_LEN * NH * HD * 2);   // 16 MB
  __bf16* Kr     = (__bf16*)alloc((size_t)S_LEN * NKV * HD * 2);  // 4 MB
  __bf16* Vt     = (__bf16*)alloc((size_t)S_LEN * NKV * HD * 2);  // 4 MB
  __bf16* attn   = hid_bf;  // hidden_bf16 dead after GEMM1

  {
    int n4 = S_LEN * HID / 4;
    cast_bf16_kernel<<<(n4 + 255) / 256, 256, 0, stream>>>((const float4*)hidden, hid_bf, n4);
  }
  transpose_cast_kernel<<<dim3(QKV_N / 32, HID / 32), dim3(32, 8), 0, stream>>>(Wqkv, wqkvT, HID, QKV_N);
  transpose_cast_kernel<<<dim3(HID / 32, HID / 32), dim3(32, 8), 0, stream>>>(Wo, woT, HID, HID);
  gemm8p_kernel<__bf16><<<dim3(QKV_N / 256, S_LEN / 256), 512, 0, stream>>>(
      hid_bf, wqkvT, qkv, S_LEN, QKV_N, HID);
  {
    int total = S_LEN * NQK * 64;
    rope_kernel<<<total / 256, 256, 0, stream>>>(qkv, positions, Qr, Kr);
  }
  transpose_v_kernel<<<dim3(S_LEN / 32, HD / 32, NKV), dim3(32, 8), 0, stream>>>(qkv, Vt);
  attn_kernel<<<NH * (S_LEN / 64), 256, 0, stream>>>(Qr, Kr, Vt, attn);
  gemm8p_kernel<float><<<dim3(HID / 256, S_LEN / 256), 512, 0, stream>>>(
      attn, woT, out, S_LEN, HID, HID);
}

// Round 4
// 496.873 us; speedup vs baseline: 1.2567x; 1.0862x over previous
//
#include <hip/hip_runtime.h>
#include <math.h>
#include <stdint.h>

// Problem constants
#define S_LEN 2048
#define HID 4096
#define NH 32
#define NKV 8
#define HD 128
#define QKV_N ((NH + 2*NKV) * HD)   // 6144
#define NQK (NH + NKV)              // 40
static __device__ __constant__ const float SCALE_F = 0.08838834764831845f; // 128^-0.5

typedef __bf16 bf16x8 __attribute__((ext_vector_type(8)));
typedef __bf16 bf16x4 __attribute__((ext_vector_type(4)));
typedef float  f32x4  __attribute__((ext_vector_type(4)));
typedef uint32_t u32x4 __attribute__((ext_vector_type(4)));

#define GLD_LDS(gptr, lptr) \
  __builtin_amdgcn_global_load_lds( \
      (const __attribute__((address_space(1))) uint32_t*)(gptr), \
      (__attribute__((address_space(3))) uint32_t*)(lptr), 16, 0, 0)

// ---------- cast fp32 -> bf16 (vectorized) ----------
__global__ void cast_bf16_kernel(const float4* __restrict__ in, __bf16* __restrict__ out, int n4) {
  int i = blockIdx.x * blockDim.x + threadIdx.x;
  if (i >= n4) return;
  float4 v = in[i];
  bf16x4 o = { (__bf16)v.x, (__bf16)v.y, (__bf16)v.z, (__bf16)v.w };
  *(bf16x4*)(out + (size_t)i * 4) = o;
}

// ---------- transpose + cast: in[R][C] fp32 -> out[C][R] bf16 ----------
__global__ void transpose_cast_kernel(const float* __restrict__ in, __bf16* __restrict__ out,
                                      int R, int C) {
  __shared__ float tile[32][33];
  int bx = blockIdx.x * 32;  // col of in
  int by = blockIdx.y * 32;  // row of in
  int tx = threadIdx.x, ty = threadIdx.y;
  for (int i = 0; i < 32; i += 8)
    tile[ty + i][tx] = in[(size_t)(by + ty + i) * C + bx + tx];
  __syncthreads();
  for (int i = 0; i < 32; i += 8)
    out[(size_t)(bx + ty + i) * R + by + tx] = (__bf16)tile[tx][ty + i];
}

// ---------- V transpose: Vt[kvh][d][s] = qkv[s][(NH+NKV)*HD + kvh*HD + d] ----------
__global__ void transpose_v_kernel(const __bf16* __restrict__ qkv, __bf16* __restrict__ Vt) {
  __shared__ __bf16 tile[32][33];
  int kvh = blockIdx.z;
  int sb = blockIdx.x * 32;
  int db = blockIdx.y * 32;
  int tx = threadIdx.x, ty = threadIdx.y;
  const __bf16* src = qkv + (size_t)(NH + NKV) * HD + (size_t)kvh * HD;
  for (int i = 0; i < 32; i += 8)
    tile[ty + i][tx] = src[(size_t)(sb + ty + i) * QKV_N + db + tx];
  __syncthreads();
  for (int i = 0; i < 32; i += 8)
    Vt[((size_t)kvh * HD + db + ty + i) * S_LEN + sb + tx] = tile[tx][ty + i];
}

// ---------- RoPE: split qkv -> Qr [S][NH][HD], Kr [S][NKV][HD] with rotation ----------
__global__ void rope_kernel(const __bf16* __restrict__ qkv, const int* __restrict__ pos,
                            __bf16* __restrict__ Qr, __bf16* __restrict__ Kr) {
  int idx = blockIdx.x * blockDim.x + threadIdx.x;
  int half = idx & 63;         // 0..63
  int t = idx >> 6;
  int hh = t % NQK;
  int s = t / NQK;
  if (s >= S_LEN) return;
  float p = (float)pos[s];
  float inv_freq = exp2f((float)half * -0.2076205059304601f);
  float ang = p * inv_freq;
  float cs = cosf(ang), sn = sinf(ang);
  const __bf16* src; __bf16* dst;
  if (hh < NH) {
    src = qkv + (size_t)s * QKV_N + (size_t)hh * HD;
    dst = Qr + ((size_t)s * NH + hh) * HD;
  } else {
    int kh = hh - NH;
    src = qkv + (size_t)s * QKV_N + (size_t)NH * HD + (size_t)kh * HD;
    dst = Kr + ((size_t)s * NKV + kh) * HD;
  }
  float x1 = (float)src[half], x2 = (float)src[half + 64];
  dst[half]      = (__bf16)(x1 * cs - x2 * sn);
  dst[half + 64] = (__bf16)(x2 * cs + x1 * sn);
}

// ===================================================================================
// 256x256-tile 8-phase bf16 GEMM, R4: register-load pipelined one phase ahead.
// Phase p = [even: vmcnt(4)] ; ISSUE ds_reads for p+1 ; s_barrier ; lgkmcnt(4|8) ;
//           16xMFMA(p) ; STAGE (asm global_load_lds, m0-based).
// - ds_reads for p+1 overlap MFMA(p): LDS pipe (~440-580 cyc) hides under matrix
//   pipe (~620 cyc) instead of serializing (R3: 1220 cyc/phase observed).
// - ONE barrier per phase. Hazard ledger (verified):
//   * DMA publish: buffer staged at end of phase q is drained by ALL waves' vmcnt(4)
//     at even-top q' >= q+3, then a barrier precedes any read-issue of it.
//   * STAGE targets are disjoint from the <=2 phases of reads pending at stage time
//     (stage touches tile t+2/t+3; pending reads touch tiles t/t+1, checked per phase).
//   * Reader-done: buffer staged at p was last lgkm-waited at <= p-2; BAR(p-1)
//     globally orders that before the post-BAR(p) stage.
// - vmcnt(4) at EVEN phase tops; steady-state in-flight = 8 loads (4 stages).
// - Everything memory-touching in the loop is inline asm -> SIInsertWaitcnts sees
//   nothing pending, cannot insert hidden drains (rule #18 sched_barrier after waits).
// - T1 column-chunk XCD swizzle: XCD i gets bn-columns [i*nx/8, (i+1)*nx/8) ->
//   per-XCD traffic 16MB A + nx/8*2MB B (R3 row-chunk was 50MB -> FETCH doubled).
// ===================================================================================
template <typename OutT>
__global__ __launch_bounds__(512, 2) void gemm8p_kernel(const __bf16* __restrict__ A,
                                                        const __bf16* __restrict__ Bt,
                                                        OutT* __restrict__ C,
                                                        int M, int N, int K) {
  __shared__ __align__(16) __bf16 sA[2][2][256 * 32];
  __shared__ __align__(16) __bf16 sB[2][2][256 * 32];
  const int tid = threadIdx.x;
  const int lane = tid & 63;
  const int wave = tid >> 6;
  const int quad = lane >> 4;
  const int l16 = lane & 15;
  const int wm = (wave >> 2) * 128;   // 2 M-warps
  const int wn = (wave & 3) * 64;     // 4 N-warps

  // T1 column-chunk: linear id (x fastest) -> xcd = lin&7 owns nx/8 bn-columns.
  const int nx = gridDim.x;
  size_t bm, bn;
  if (gridDim.y == 8 && (nx & 7) == 0) {
    int lin = blockIdx.y * nx + blockIdx.x;
    int j = lin >> 3, xcd = lin & 7;
    bm = (size_t)(j & 7) * 256;
    bn = (size_t)(xcd * (nx >> 3) + (j >> 3)) * 256;
  } else {
    bm = (size_t)blockIdx.y * 256;
    bn = (size_t)blockIdx.x * 256;
  }

  const int NT = K >> 6;              // K-tiles of 64 (K=4096 -> 64, even)
  const int rsw = (l16 >> 1) & 3;     // read-side chunk swizzle

  f32x4 acc[8][4] = {};
  bf16x8 aR[2][4], bR[2][4];          // double register sets (ping-pong by phase)

  // ---- per-thread global staging addresses (running pointers, +64 B per stage) ----
  // chunk c = it*512+tid ; row = c>>2 ; ch = c&3 ; chL = ch ^ ((row>>1)&3).
  // it=1 differs from it=0 by +128 rows; chL identical for both halves.
  const int row0 = tid >> 2;
  const int chL = (tid & 3) ^ ((tid >> 3) & 3);
  const uint64_t off128 = (uint64_t)128 * K * 2;
  uint64_t aGA = (uint64_t)(uintptr_t)A + ((bm + row0) * (size_t)K) * 2 + (size_t)chL * 16;
  uint64_t bGA = (uint64_t)(uintptr_t)Bt + ((bn + row0) * (size_t)K) * 2 + (size_t)chL * 16;

  // ---- LDS byte bases ----
  typedef __attribute__((address_space(3))) __bf16 lds_bf16;
  const uint32_t sAb = (uint32_t)(uintptr_t)(lds_bf16*)&sA[0][0][0];
  const uint32_t sBb = (uint32_t)(uintptr_t)(lds_bf16*)&sB[0][0][0];
  const uint32_t wlds = (uint32_t)__builtin_amdgcn_readfirstlane(wave * 1024);
  const uint32_t aBase = sAb + (uint32_t)(((wm + l16) * 32 + (quad ^ rsw) * 8) * 2);
  const uint32_t bBase = sBb + (uint32_t)(((wn + l16) * 32 + (quad ^ rsw) * 8) * 2);
  // strides (bytes): buf 32768, khalf 16384, 16-row fragment 1024, ih 4096.

#define LDSA(bf, kk) (sAb + (bf) * 32768u + (kk) * 16384u)
#define LDSB(bf, kk) (sBb + (bf) * 32768u + (kk) * 16384u)

  // asm global_load_lds: LDS dest = m0 + lane*16 (wave-uniform base), per-lane vaddr.
#define STAGE_ASM(ga, ldsbase) \
  asm volatile("s_mov_b32 m0, %0\n\t" \
               "global_load_lds_dwordx4 %2, off\n\t" \
               "s_mov_b32 m0, %1\n\t" \
               "global_load_lds_dwordx4 %3, off" \
               :: "s"((ldsbase) + wlds), "s"((ldsbase) + wlds + 8192u), \
                  "v"(ga), "v"((ga) + off128) : "memory")

#define DSRD4(dst, baseaddr) do {                                                 \
    u32x4 t0_, t1_, t2_, t3_;                                                     \
    asm volatile("ds_read_b128 %0, %4\n\t"                                        \
                 "ds_read_b128 %1, %4 offset:1024\n\t"                            \
                 "ds_read_b128 %2, %4 offset:2048\n\t"                            \
                 "ds_read_b128 %3, %4 offset:3072"                                \
                 : "=&v"(t0_), "=&v"(t1_), "=&v"(t2_), "=&v"(t3_)                 \
                 : "v"(baseaddr));                                                \
    dst[0] = __builtin_bit_cast(bf16x8, t0_);                                     \
    dst[1] = __builtin_bit_cast(bf16x8, t1_);                                     \
    dst[2] = __builtin_bit_cast(bf16x8, t2_);                                     \
    dst[3] = __builtin_bit_cast(bf16x8, t3_);                                     \
  } while (0)

#define ISSUE_A(set, bf, kk, ih) DSRD4(aR[set], aBase + (bf) * 32768u + (kk) * 16384u + (ih) * 4096u)
#define ISSUE_B(set, bf, kk)     DSRD4(bR[set], bBase + (bf) * 32768u + (kk) * 16384u)

#define MFMA16(as, bs, ih) do {                                                   \
    __builtin_amdgcn_s_setprio(1);                                                \
    _Pragma("unroll")                                                             \
    for (int i_ = 0; i_ < 4; ++i_)                                                \
      _Pragma("unroll")                                                           \
      for (int j_ = 0; j_ < 4; ++j_)                                              \
        acc[(ih) * 4 + i_][j_] = __builtin_amdgcn_mfma_f32_16x16x32_bf16(         \
            aR[as][i_], bR[bs][j_], acc[(ih) * 4 + i_][j_], 0, 0, 0);             \
    __builtin_amdgcn_s_setprio(0);                                                \
    __builtin_amdgcn_sched_barrier(0);                                            \
  } while (0)

#define BAR() __builtin_amdgcn_s_barrier()
#define LGKM4() do { asm volatile("s_waitcnt lgkmcnt(4)");                        \
                     __builtin_amdgcn_sched_barrier(0); } while (0)
#define LGKM8() do { asm volatile("s_waitcnt lgkmcnt(8)");                        \
                     __builtin_amdgcn_sched_barrier(0); } while (0)
#define VMCNT4() do { asm volatile("s_waitcnt vmcnt(4)");                         \
                      __builtin_amdgcn_sched_barrier(0); } while (0)

  // ---- prologue: tile0 (4 halves) + tile1 k0; drain tile0; publish; reads for p0 ----
  STAGE_ASM(aGA,        LDSA(0, 0));
  STAGE_ASM(bGA,        LDSB(0, 0));
  STAGE_ASM(aGA + 64,   LDSA(0, 1));
  STAGE_ASM(bGA + 64,   LDSB(0, 1));
  STAGE_ASM(aGA + 128,  LDSA(1, 0));
  STAGE_ASM(bGA + 128,  LDSB(1, 0));
  aGA += 192; bGA += 192;
  asm volatile("s_waitcnt vmcnt(8)");
  __builtin_amdgcn_sched_barrier(0);
  BAR();
  ISSUE_A(0, 0, 0, 0); ISSUE_B(0, 0, 0);   // operands for p0 (8 reads in flight)

  for (int u = 0; u < (NT >> 1); ++u) {
    // ---- p0: MFMA(buf0,kk0,ih0); issue A(buf0,kk0,ih1); stage sA[1][1] ----
    VMCNT4();
    ISSUE_A(1, 0, 0, 1);
    BAR();
    LGKM4();
    MFMA16(0, 0, 0);
    STAGE_ASM(aGA, LDSA(1, 1)); aGA += 64;
    // ---- p1: MFMA(ih1); issue A+B(buf0,kk1); stage sB[1][1] ----
    ISSUE_A(0, 0, 1, 0); ISSUE_B(1, 0, 1);
    BAR();
    LGKM8();
    MFMA16(1, 0, 1);
    STAGE_ASM(bGA, LDSB(1, 1)); bGA += 64;
    // ---- p2 ----
    VMCNT4();
    ISSUE_A(1, 0, 1, 1);
    BAR();
    LGKM4();
    MFMA16(0, 1, 0);
    STAGE_ASM(aGA, LDSA(0, 0)); aGA += 64;
    // ---- p3 ----
    ISSUE_A(0, 1, 0, 0); ISSUE_B(0, 1, 0);
    BAR();
    LGKM8();
    MFMA16(1, 1, 1);
    STAGE_ASM(bGA, LDSB(0, 0)); bGA += 64;
    // ---- p4 ----
    VMCNT4();
    ISSUE_A(1, 1, 0, 1);
    BAR();
    LGKM4();
    MFMA16(0, 0, 0);
    STAGE_ASM(aGA, LDSA(0, 1)); aGA += 64;
    // ---- p5 ----
    ISSUE_A(0, 1, 1, 0); ISSUE_B(1, 1, 1);
    BAR();
    LGKM8();
    MFMA16(1, 0, 1);
    STAGE_ASM(bGA, LDSB(0, 1)); bGA += 64;
    // ---- p6 ----
    VMCNT4();
    ISSUE_A(1, 1, 1, 1);
    BAR();
    LGKM4();
    MFMA16(0, 1, 0);
    STAGE_ASM(aGA, LDSA(1, 0)); aGA += 64;
    // ---- p7 ----
    ISSUE_A(0, 0, 0, 0); ISSUE_B(0, 0, 0);
    BAR();
    LGKM8();
    MFMA16(1, 1, 1);
    STAGE_ASM(bGA, LDSB(1, 0)); bGA += 64;
  }
  // tail stages past K read <=384 B beyond the matrix into adjacent workspace
  // buffers (never past the workspace) and fill only dead LDS regions.

  asm volatile("s_waitcnt vmcnt(0) lgkmcnt(0)");
  __builtin_amdgcn_sched_barrier(0);

  #pragma unroll
  for (int i = 0; i < 8; ++i)
    #pragma unroll
    for (int j = 0; j < 4; ++j)
      #pragma unroll
      for (int r = 0; r < 4; ++r) {
        size_t row = bm + wm + i * 16 + quad * 4 + r;
        size_t col = bn + wn + j * 16 + l16;
        C[row * (size_t)N + col] = (OutT)acc[i][j][r];
      }

#undef LDSA
#undef LDSB
#undef STAGE_ASM
#undef DSRD4
#undef ISSUE_A
#undef ISSUE_B
#undef MFMA16
#undef BAR
#undef LGKM4
#undef LGKM8
#undef VMCNT4
}

// ---------- flash attention v3 (causal, GQA) — 2-phase pipelined staging ----------
// (unchanged from R2)
__global__ __launch_bounds__(256, 2) void attn_kernel(const __bf16* __restrict__ Qr,
                                                      const __bf16* __restrict__ Kr,
                                                      const __bf16* __restrict__ Vt,
                                                      __bf16* __restrict__ O) {
  __shared__ __align__(16) char smem[73728];
  __bf16* Ps = (__bf16*)(smem + 65536);    // [4 wave][16 q][64 key], swizzled

  const int bid = blockIdx.x;
  const int h = bid & (NH - 1);
  const int qb = (S_LEN / 64 - 1) - (bid >> 5);     // longest first
  const int kvh = h >> 2;                            // REP = 4
  const int tid = threadIdx.x;
  const int lane = tid & 63, wave = tid >> 6;
  const int quad = lane >> 4, l16 = lane & 15;
  const int sw = l16 & 7;                            // swizzle key
  const int q0 = qb * 64;

#define STAGE_KV(kbase, bufv) do {                                                 \
    char* kd_ = smem + (bufv) * 16384;                                             \
    char* vd_ = smem + 32768 + (bufv) * 16384;                                     \
    _Pragma("unroll")                                                              \
    for (int pass_ = 0; pass_ < 4; ++pass_) {                                      \
      int c_ = pass_ * 256 + tid;                                                  \
      int row_ = c_ >> 4, ch_ = c_ & 15;                                           \
      int chs_ = ch_ ^ (row_ & 7);                                                 \
      GLD_LDS(&Kr[(size_t)((kbase) + row_) * (NKV * HD) + (size_t)kvh * HD + chs_ * 8], \
              kd_ + c_ * 16);                                                      \
    }                                                                              \
    _Pragma("unroll")                                                              \
    for (int pass_ = 0; pass_ < 4; ++pass_) {                                      \
      int c_ = pass_ * 256 + tid;                                                  \
      int d_ = c_ >> 3, ch_ = c_ & 7;                                              \
      int chs_ = ch_ ^ (d_ & 7);                                                   \
      GLD_LDS(&Vt[((size_t)kvh * HD + d_) * S_LEN + (kbase) + chs_ * 8],           \
              vd_ + c_ * 16);                                                      \
    }                                                                              \
  } while (0)

  bf16x8 qf[4];
  {
    const __bf16* qp = Qr + (size_t)(q0 + wave * 16 + l16) * (NH * HD) + (size_t)h * HD + quad * 8;
    for (int kk = 0; kk < 4; ++kk) qf[kk] = *(const bf16x8*)(qp + kk * 32);
  }
  f32x4 oacc[8] = {};
  float m2 = -INFINITY, l_i = 0.0f;
  const float C2 = SCALE_F * 1.4426950408889634f;

  int buf = 0;
  STAGE_KV(0, 0);
  for (int kb = 0; kb <= q0; kb += 64) {
    __syncthreads();
    if (kb + 64 <= q0) STAGE_KV(kb + 64, buf ^ 1);

    const __bf16* Ks = (const __bf16*)(smem + buf * 16384);
    const __bf16* Vs = (const __bf16*)(smem + 32768 + buf * 16384);

    f32x4 sc[4] = {};
    __builtin_amdgcn_s_setprio(1);
    for (int jt = 0; jt < 4; ++jt)
      for (int kk = 0; kk < 4; ++kk) {
        bf16x8 kf = *(const bf16x8*)&Ks[(jt * 16 + l16) * 128 + ((kk * 4 + quad) ^ sw) * 8];
        sc[jt] = __builtin_amdgcn_mfma_f32_16x16x32_bf16(kf, qf[kk], sc[jt], 0, 0, 0);
      }
    __builtin_amdgcn_s_setprio(0);

    float s[16];
    for (int jt = 0; jt < 4; ++jt)
      for (int r = 0; r < 4; ++r) s[jt * 4 + r] = sc[jt][r];
    if (kb == q0) {
      int qloc = wave * 16 + l16;
      for (int jt = 0; jt < 4; ++jt)
        for (int r = 0; r < 4; ++r)
          if (jt * 16 + quad * 4 + r > qloc) s[jt * 4 + r] = -INFINITY;
    }
    float mx = s[0];
    for (int i = 1; i < 16; ++i) mx = fmaxf(mx, s[i]);
    mx = fmaxf(mx, __shfl_xor(mx, 16, 64));
    mx = fmaxf(mx, __shfl_xor(mx, 32, 64));
    float m2new = fmaxf(m2, mx * C2);
    float alpha = exp2f(m2 - m2new);
    float pv[16], sum = 0.0f;
    for (int i = 0; i < 16; ++i) { pv[i] = exp2f(fmaf(s[i], C2, -m2new)); sum += pv[i]; }
    sum += __shfl_xor(sum, 16, 64);
    sum += __shfl_xor(sum, 32, 64);
    l_i = l_i * alpha + sum;
    m2 = m2new;
    for (int dt = 0; dt < 8; ++dt) oacc[dt] *= alpha;

    __bf16* pw = Ps + wave * 1024 + l16 * 64;
    for (int jt = 0; jt < 4; ++jt) {
      bf16x4 pk = { (__bf16)pv[jt*4+0], (__bf16)pv[jt*4+1], (__bf16)pv[jt*4+2], (__bf16)pv[jt*4+3] };
      int chunk = jt * 2 + (quad >> 1);
      *(bf16x4*)&pw[((chunk ^ sw) * 8) + (quad & 1) * 4] = pk;
    }
    __builtin_amdgcn_s_setprio(1);
    for (int half = 0; half < 2; ++half) {
      bf16x8 pf = *(const bf16x8*)&pw[((half * 4 + quad) ^ sw) * 8];
      for (int dt = 0; dt < 8; ++dt) {
        bf16x8 vf = *(const bf16x8*)&Vs[(dt * 16 + l16) * 64 + ((half * 4 + quad) ^ sw) * 8];
        oacc[dt] = __builtin_amdgcn_mfma_f32_16x16x32_bf16(vf, pf, oacc[dt], 0, 0, 0);
      }
    }
    __builtin_amdgcn_s_setprio(0);
    buf ^= 1;
  }
  __syncthreads();

#undef STAGE_KV

  float* scr = (float*)smem + wave * 2112;
  float inv = 1.0f / l_i;
  for (int dt = 0; dt < 8; ++dt) {
    f32x4 v = oacc[dt] * inv;
    *(f32x4*)&scr[l16 * 132 + dt * 16 + quad * 4] = v;
  }
  for (int it = 0; it < 4; ++it) {
    int c = it * 64 + lane;
    int row = c >> 4, ch = c & 15;
    const float* sp = &scr[row * 132 + ch * 8];
    f32x4 a = *(const f32x4*)sp;
    f32x4 b = *(const f32x4*)(sp + 4);
    bf16x8 o = { (__bf16)a[0], (__bf16)a[1], (__bf16)a[2], (__bf16)a[3],
                 (__bf16)b[0], (__bf16)b[1], (__bf16)b[2], (__bf16)b[3] };
    *(bf16x8*)&O[(size_t)(q0 + wave * 16 + row) * (NH * HD) + (size_t)h * HD + ch * 8] = o;
  }
}

extern "C" void kernel_launch(void* const* d_in, const int* in_sizes, int n_in,
                              void* d_out, int out_size, void* d_ws, size_t ws_size,
                              hipStream_t stream) {
  const float* hidden    = (const float*)d_in[0];
  const int*   positions = (const int*)d_in[1];
  const float* Wqkv      = (const float*)d_in[2];
  const float* Wo        = (const float*)d_in[3];
  float* out = (float*)d_out;

  char* p = (char*)d_ws;
  auto alloc = [&](size_t bytes) { char* r = p; p += (bytes + 255) & ~(size_t)255; return r; };
  __bf16* hid_bf = (__bf16*)alloc((size_t)S_LEN * HID * 2);       // 16 MB (reused as attn_out)
  __bf16* wqkvT  = (__bf16*)alloc((size_t)QKV_N * HID * 2);       // 48 MB  [6144][4096]
  __bf16* woT    = (__bf16*)alloc((size_t)HID * HID * 2);         // 32 MB  [4096][4096]
  __bf16* qkv    = (__bf16*)alloc((size_t)S_LEN * QKV_N * 2);     // 24 MB
  __bf16* Qr     = (__bf16*)alloc((size_t)S_LEN * NH * HD * 2);   // 16 MB
  __bf16* Kr     = (__bf16*)alloc((size_t)S_LEN * NKV * HD * 2);  // 4 MB
  __bf16* Vt     = (__bf16*)alloc((size_t)S_LEN * NKV * HD * 2);  // 4 MB
  __bf16* attn   = hid_bf;  // hidden_bf16 dead after GEMM1

  {
    int n4 = S_LEN * HID / 4;
    cast_bf16_kernel<<<(n4 + 255) / 256, 256, 0, stream>>>((const float4*)hidden, hid_bf, n4);
  }
  transpose_cast_kernel<<<dim3(QKV_N / 32, HID / 32), dim3(32, 8), 0, stream>>>(Wqkv, wqkvT, HID, QKV_N);
  transpose_cast_kernel<<<dim3(HID / 32, HID / 32), dim3(32, 8), 0, stream>>>(Wo, woT, HID, HID);
  gemm8p_kernel<__bf16><<<dim3(QKV_N / 256, S_LEN / 256), 512, 0, stream>>>(
      hid_bf, wqkvT, qkv, S_LEN, QKV_N, HID);
  {
    int total = S_LEN * NQK * 64;
    rope_kernel<<<total / 256, 256, 0, stream>>>(qkv, positions, Qr, Kr);
  }
  transpose_v_kernel<<<dim3(S_LEN / 32, HD / 32, NKV), dim3(32, 8), 0, stream>>>(qkv, Vt);
  attn_kernel<<<NH * (S_LEN / 64), 256, 0, stream>>>(Qr, Kr, Vt, attn);
  gemm8p_kernel<float><<<dim3(HID / 256, S_LEN / 256), 512, 0, stream>>>(
      attn, woT, out, S_LEN, HID, HID);
}